// Round 3
// baseline (266.728 us; speedup 1.0000x reference)
//
#include <hip/hip_runtime.h>

#define B 8
#define N 2048
#define M 2048
#define DIN 256
#define E 128
#define ALPHA 0.01f

typedef __attribute__((ext_vector_type(8))) short bf16x8;
typedef __attribute__((ext_vector_type(4))) float f32x4;

__device__ inline ushort f2bf(float x) {
  unsigned u = __float_as_uint(x);
  u = (u + 0x7FFFu + ((u >> 16) & 1u)) >> 16;  // RNE
  return (ushort)u;
}

// ---------------------------------------------------------------------------
// K0: v1[k] = sum_e W1[k][e]*a1[e], v2[k] = sum_e W1[k][e]*a1[128+e]
// ---------------------------------------------------------------------------
__global__ __launch_bounds__(256) void prep_v_kernel(
    const float* __restrict__ W1, const float* __restrict__ a1,
    float* __restrict__ v1, float* __restrict__ v2) {
  int k = threadIdx.x;
  float s1 = 0.f, s2 = 0.f;
#pragma unroll 8
  for (int e = 0; e < E; ++e) {
    float w = W1[k * E + e];
    s1 += w * a1[e];
    s2 += w * a1[E + e];
  }
  v1[k] = s1;
  v2[k] = s2;
}

// ---------------------------------------------------------------------------
// K1: att1[row] = dot(input1[row,:], v1); att2 likewise. One wave per row.
// ---------------------------------------------------------------------------
__global__ __launch_bounds__(256) void att_kernel(
    const float* __restrict__ in1, const float* __restrict__ in2,
    const float* __restrict__ v1, const float* __restrict__ v2,
    float* __restrict__ att1, float* __restrict__ att2) {
  int wave = blockIdx.x * 4 + (threadIdx.x >> 6);
  int lane = threadIdx.x & 63;
  const float* src;
  const float* v;
  float* dst;
  int row;
  if (wave < B * N) {
    src = in1; v = v1; dst = att1; row = wave;
  } else {
    src = in2; v = v2; dst = att2; row = wave - B * N;
  }
  float4 x = *(const float4*)(src + (size_t)row * DIN + lane * 4);
  float4 vv = *(const float4*)(v + lane * 4);
  float d = x.x * vv.x + x.y * vv.y + x.z * vv.z + x.w * vv.w;
#pragma unroll
  for (int off = 32; off; off >>= 1) d += __shfl_down(d, off, 64);
  if (lane == 0) dst[row] = d;
}

// ---------------------------------------------------------------------------
// K2: Wh2 = input2 @ W1, fp32 compute, epilogue packs bf16 into
// MFMA-B-fragment layout: Wb[(m>>3)*1024 + e*8 + (m&7)].
// ---------------------------------------------------------------------------
__global__ __launch_bounds__(256) void wh2_kernel(
    const float* __restrict__ in2, const float* __restrict__ W1,
    ushort* __restrict__ Wb) {
  __shared__ float a[32][DIN];  // 32 KB
  int r0 = blockIdx.x * 32;
#pragma unroll
  for (int i = 0; i < 8; ++i) {
    int f = (threadIdx.x + i * 256) * 4;
    int r = f >> 8, k = f & 255;
    *(float4*)&a[r][k] = *(const float4*)(in2 + (size_t)(r0 + r) * DIN + k);
  }
  __syncthreads();
  int c  = (threadIdx.x & 31) * 4;
  int tr = (threadIdx.x >> 5) * 4;
  float acc[4][4] = {};
  for (int k = 0; k < DIN; ++k) {
    float4 b = *(const float4*)(W1 + k * E + c);
#pragma unroll
    for (int r = 0; r < 4; ++r) {
      float av = a[tr + r][k];
      acc[r][0] += av * b.x;
      acc[r][1] += av * b.y;
      acc[r][2] += av * b.z;
      acc[r][3] += av * b.w;
    }
  }
#pragma unroll
  for (int r = 0; r < 4; ++r) {
    int m = r0 + tr + r;
    size_t gbase = (size_t)(m >> 3) * 128 * 8 + (m & 7);
#pragma unroll
    for (int j = 0; j < 4; ++j)
      Wb[gbase + (size_t)(c + j) * 8] = f2bf(acc[r][j]);
  }
}

// ---------------------------------------------------------------------------
// K3 (fused softmax + context): per 32-row tile,
//   phase 0: stage att2[b,:], mask[b,:], att1 rows in LDS
//   phase 1: two-pass per-row max & sum (scores recomputed from rank-1 form)
//   phase 2: K-loop: probs computed in registers directly in MFMA-A layout,
//            stored fp32 to global once, MFMA'd against packed Wb tiles.
// Eliminates the 134 MB probs HBM re-read and all LDS-A staging.
// ---------------------------------------------------------------------------
__global__ __launch_bounds__(256) void fused_kernel(
    const float* __restrict__ att1, const float* __restrict__ att2,
    const float* __restrict__ mask, const ushort* __restrict__ Wb,
    float* __restrict__ probs, float* __restrict__ ctx) {
  __shared__ float att2s[M];        // 8 KB
  __shared__ float masks[M];        // 8 KB
  __shared__ float att1s[32];
  __shared__ float red[32][9];      // padded partials
  __shared__ float rowmax[32];
  __shared__ float rowinv[32];
  __shared__ ushort ldsB[8 * 128 * 8];  // 16 KB

  int rt = blockIdx.x & 63;
  int b  = blockIdx.x >> 6;
  int row0 = b * N + rt * 32;
  int t = threadIdx.x;

  // phase 0: stage batch vectors
#pragma unroll
  for (int i = 0; i < 2; ++i) {
    int idx = (t + i * 256) * 4;
    *(float4*)&att2s[idx] = *(const float4*)(att2 + b * M + idx);
    *(float4*)&masks[idx] = *(const float4*)(mask + b * M + idx);
  }
  if (t < 32) att1s[t] = att1[row0 + t];
  __syncthreads();

  // phase 1: per-row max then sum (8 threads per row, 256 m each)
  int r = t >> 3, ch = t & 7;
  float a1r = att1s[r];
  float mx = -1e30f;
  for (int m = ch * 256; m < ch * 256 + 256; ++m) {
    float s = a1r + att2s[m];
    s = s > 0.f ? s : ALPHA * s;
    s += masks[m];
    mx = fmaxf(mx, s);
  }
  red[r][ch] = mx;
  __syncthreads();
  if (t < 32) {
    float m2 = red[t][0];
#pragma unroll
    for (int j = 1; j < 8; ++j) m2 = fmaxf(m2, red[t][j]);
    rowmax[t] = m2;
  }
  __syncthreads();
  float rmax = rowmax[r];
  float sum = 0.f;
  for (int m = ch * 256; m < ch * 256 + 256; ++m) {
    float s = a1r + att2s[m];
    s = s > 0.f ? s : ALPHA * s;
    s += masks[m];
    sum += __expf(s - rmax);
  }
  red[r][ch] = sum;
  __syncthreads();
  if (t < 32) {
    float s2 = 0.f;
#pragma unroll
    for (int j = 0; j < 8; ++j) s2 += red[t][j];
    rowinv[t] = 1.f / s2;
  }
  __syncthreads();

  // phase 2: K-loop with MFMA
  int lane = t & 63;
  int w = t >> 6;
  int quad = lane >> 4;
  int l16 = lane & 15;
  int m0w = (w & 1) * 16;
  int n0w = (w >> 1) * 64;
  float a1v  = att1s[m0w + l16];
  float rmxL = rowmax[m0w + l16];
  float rinL = rowinv[m0w + l16];
  bool do_store = (n0w == 0);  // waves 0,1 own the probs write (rows 0-31)
  float* prow = probs + (size_t)(row0 + m0w + l16) * M;

  f32x4 acc[4] = {};

  for (int k0 = 0; k0 < M; k0 += 64) {
    // stage B: contiguous 16 KB (8 groups x 128 e x 8 k bf16)
    {
      const char* g =
          (const char*)(Wb + (size_t)(b * 256 + (k0 >> 3)) * 128 * 8);
      char* l = (char*)ldsB;
      int base = w * 4096 + lane * 16;
#pragma unroll
      for (int i = 0; i < 4; ++i) {
        int off = base + i * 1024;
        __builtin_amdgcn_global_load_lds(
            (const __attribute__((address_space(1))) void*)(g + off),
            (__attribute__((address_space(3))) void*)(l + off), 16, 0, 0);
      }
    }
    __syncthreads();
#pragma unroll
    for (int ks = 0; ks < 64; ks += 32) {
      int kb = k0 + ks + quad * 8;
      bf16x8 af;
      float p[8];
#pragma unroll
      for (int j = 0; j < 8; ++j) {
        float s = a1v + att2s[kb + j];
        s = s > 0.f ? s : ALPHA * s;
        s += masks[kb + j];
        float pe = __expf(s - rmxL) * rinL;
        p[j] = pe;
        af[j] = (short)f2bf(pe);
      }
      if (do_store) {
        *(float4*)(prow + kb)     = make_float4(p[0], p[1], p[2], p[3]);
        *(float4*)(prow + kb + 4) = make_float4(p[4], p[5], p[6], p[7]);
      }
      int gl = (ks >> 3) + quad;
#pragma unroll
      for (int cf = 0; cf < 4; ++cf) {
        int n = n0w + cf * 16 + l16;
        bf16x8 bfb = *(const bf16x8*)&ldsB[((size_t)gl * 128 + n) * 8];
        acc[cf] =
            __builtin_amdgcn_mfma_f32_16x16x32_bf16(af, bfb, acc[cf], 0, 0, 0);
      }
    }
    __syncthreads();
  }
  // epilogue: C/D layout col=lane&15, row=quad*4+reg
#pragma unroll
  for (int cf = 0; cf < 4; ++cf) {
    int nn = n0w + cf * 16 + l16;
#pragma unroll
    for (int reg = 0; reg < 4; ++reg) {
      int rr = row0 + m0w + quad * 4 + reg;
      ctx[(size_t)rr * E + nn] = acc[cf][reg];
    }
  }
}

extern "C" void kernel_launch(void* const* d_in, const int* in_sizes, int n_in,
                              void* d_out, int out_size, void* d_ws,
                              size_t ws_size, hipStream_t stream) {
  (void)in_sizes; (void)n_in; (void)out_size; (void)ws_size;
  const float* in1  = (const float*)d_in[0];  // (B,N,DIN)
  const float* in2  = (const float*)d_in[1];  // (B,M,DIN)
  const float* mask = (const float*)d_in[2];  // (B,1,M)
  const float* W1   = (const float*)d_in[3];  // (DIN,E)
  const float* a1   = (const float*)d_in[4];  // (2E,1)

  float* ws   = (float*)d_ws;
  float* v1   = ws;                 // 256
  float* v2   = v1 + DIN;           // 256
  float* att1 = v2 + DIN;           // B*N
  float* att2 = att1 + B * N;       // B*M
  ushort* Wb  = (ushort*)(att2 + B * M);  // B*M*E bf16 packed (8.4 MB)

  float* ctx   = (float*)d_out;                 // B*N*E
  float* probs = ctx + (size_t)B * N * E;       // B*N*M

  hipLaunchKernelGGL(prep_v_kernel, dim3(1), dim3(256), 0, stream, W1, a1, v1, v2);
  hipLaunchKernelGGL(att_kernel, dim3((B * N + B * M) / 4), dim3(256), 0, stream,
                     in1, in2, v1, v2, att1, att2);
  hipLaunchKernelGGL(wh2_kernel, dim3(B * M / 32), dim3(256), 0, stream,
                     in2, W1, Wb);
  hipLaunchKernelGGL(fused_kernel, dim3(B * N / 32), dim3(256), 0, stream,
                     att1, att2, mask, Wb, probs, ctx);
}

// Round 4
// 228.519 us; speedup vs baseline: 1.1672x; 1.1672x over previous
//
#include <hip/hip_runtime.h>

#define B 8
#define N 2048
#define M 2048
#define DIN 256
#define E 128
#define ALPHA 0.01f

typedef __attribute__((ext_vector_type(8))) short bf16x8;
typedef __attribute__((ext_vector_type(4))) float f32x4;

__device__ inline ushort f2bf(float x) {
  unsigned u = __float_as_uint(x);
  u = (u + 0x7FFFu + ((u >> 16) & 1u)) >> 16;  // RNE
  return (ushort)u;
}

__device__ inline float leaky_mask(float a1r, float a2, float mk) {
  float s = a1r + a2;
  s = s > 0.f ? s : ALPHA * s;
  return s + mk;
}

// ---------------------------------------------------------------------------
// K0: v1[k] = sum_e W1[k][e]*a1[e], v2[k] = sum_e W1[k][e]*a1[128+e]
// ---------------------------------------------------------------------------
__global__ __launch_bounds__(256) void prep_v_kernel(
    const float* __restrict__ W1, const float* __restrict__ a1,
    float* __restrict__ v1, float* __restrict__ v2) {
  int k = threadIdx.x;
  float s1 = 0.f, s2 = 0.f;
#pragma unroll 8
  for (int e = 0; e < E; ++e) {
    float w = W1[k * E + e];
    s1 += w * a1[e];
    s2 += w * a1[E + e];
  }
  v1[k] = s1;
  v2[k] = s2;
}

// ---------------------------------------------------------------------------
// K1: att1[row] = dot(input1[row,:], v1); att2 likewise. One wave per row.
// ---------------------------------------------------------------------------
__global__ __launch_bounds__(256) void att_kernel(
    const float* __restrict__ in1, const float* __restrict__ in2,
    const float* __restrict__ v1, const float* __restrict__ v2,
    float* __restrict__ att1, float* __restrict__ att2) {
  int wave = blockIdx.x * 4 + (threadIdx.x >> 6);
  int lane = threadIdx.x & 63;
  const float* src;
  const float* v;
  float* dst;
  int row;
  if (wave < B * N) {
    src = in1; v = v1; dst = att1; row = wave;
  } else {
    src = in2; v = v2; dst = att2; row = wave - B * N;
  }
  float4 x = *(const float4*)(src + (size_t)row * DIN + lane * 4);
  float4 vv = *(const float4*)(v + lane * 4);
  float d = x.x * vv.x + x.y * vv.y + x.z * vv.z + x.w * vv.w;
#pragma unroll
  for (int off = 32; off; off >>= 1) d += __shfl_down(d, off, 64);
  if (lane == 0) dst[row] = d;
}

// ---------------------------------------------------------------------------
// K2: Wh2 = input2 @ W1, fp32 compute, epilogue packs bf16 into
// MFMA-B-fragment layout: Wb[(m>>3)*1024 + e*8 + (m&7)].
// ---------------------------------------------------------------------------
__global__ __launch_bounds__(256) void wh2_kernel(
    const float* __restrict__ in2, const float* __restrict__ W1,
    ushort* __restrict__ Wb) {
  __shared__ float a[32][DIN];  // 32 KB
  int r0 = blockIdx.x * 32;
#pragma unroll
  for (int i = 0; i < 8; ++i) {
    int f = (threadIdx.x + i * 256) * 4;
    int r = f >> 8, k = f & 255;
    *(float4*)&a[r][k] = *(const float4*)(in2 + (size_t)(r0 + r) * DIN + k);
  }
  __syncthreads();
  int c  = (threadIdx.x & 31) * 4;
  int tr = (threadIdx.x >> 5) * 4;
  float acc[4][4] = {};
  for (int k = 0; k < DIN; ++k) {
    float4 b = *(const float4*)(W1 + k * E + c);
#pragma unroll
    for (int r = 0; r < 4; ++r) {
      float av = a[tr + r][k];
      acc[r][0] += av * b.x;
      acc[r][1] += av * b.y;
      acc[r][2] += av * b.z;
      acc[r][3] += av * b.w;
    }
  }
#pragma unroll
  for (int r = 0; r < 4; ++r) {
    int m = r0 + tr + r;
    size_t gbase = (size_t)(m >> 3) * 128 * 8 + (m & 7);
#pragma unroll
    for (int j = 0; j < 4; ++j)
      Wb[gbase + (size_t)(c + j) * 8] = f2bf(acc[r][j]);
  }
}

// ---------------------------------------------------------------------------
// K3 (new): per-row softmax stats. One wave per row, no LDS, global reads are
// L1-hot (16 KB per batch). rowmax = exact max, rowinv = 1/sum(exp(s-max)).
// ---------------------------------------------------------------------------
__global__ __launch_bounds__(256) void stats_kernel(
    const float* __restrict__ att1, const float* __restrict__ att2,
    const float* __restrict__ mask,
    float* __restrict__ rowmax, float* __restrict__ rowinv) {
  int row = blockIdx.x * 4 + (threadIdx.x >> 6);
  int lane = threadIdx.x & 63;
  int b = row >> 11;
  float a1r = att1[row];
  const float* a2 = att2 + b * M;
  const float* mk = mask + b * M;
  float mx = -1e30f;
#pragma unroll
  for (int i = 0; i < 8; ++i) {
    int m = (lane + i * 64) * 4;
    float4 av = *(const float4*)(a2 + m);
    float4 mv = *(const float4*)(mk + m);
    mx = fmaxf(mx, leaky_mask(a1r, av.x, mv.x));
    mx = fmaxf(mx, leaky_mask(a1r, av.y, mv.y));
    mx = fmaxf(mx, leaky_mask(a1r, av.z, mv.z));
    mx = fmaxf(mx, leaky_mask(a1r, av.w, mv.w));
  }
#pragma unroll
  for (int off = 32; off; off >>= 1) mx = fmaxf(mx, __shfl_xor(mx, off, 64));
  float sum = 0.f;
#pragma unroll
  for (int i = 0; i < 8; ++i) {
    int m = (lane + i * 64) * 4;
    float4 av = *(const float4*)(a2 + m);
    float4 mv = *(const float4*)(mk + m);
    sum += __expf(leaky_mask(a1r, av.x, mv.x) - mx);
    sum += __expf(leaky_mask(a1r, av.y, mv.y) - mx);
    sum += __expf(leaky_mask(a1r, av.z, mv.z) - mx);
    sum += __expf(leaky_mask(a1r, av.w, mv.w) - mx);
  }
#pragma unroll
  for (int off = 32; off; off >>= 1) sum += __shfl_xor(sum, off, 64);
  if (lane == 0) {
    rowmax[row] = mx;
    rowinv[row] = 1.f / sum;
  }
}

// ---------------------------------------------------------------------------
// K4 (fused probs + context), v2: 32 rows x 128 cols per block, 4 waves.
// Wave w: rows m0w=(w&1)*16, ALL 128 cols, k-chunk h=(w>>1) of each 128-k
// tile -> every probs element exp'd exactly ONCE, stored to global in
// MFMA-A-register layout (contiguous 32B/row/lane-group), MFMA'd vs packed
// Wb. Cross-pair (h=0 + h=1) accumulator reduce via padded LDS at the end.
// ---------------------------------------------------------------------------
__global__ __launch_bounds__(256) void fused_kernel(
    const float* __restrict__ att1, const float* __restrict__ att2,
    const float* __restrict__ mask, const float* __restrict__ rowmax,
    const float* __restrict__ rowinv, const ushort* __restrict__ Wb,
    float* __restrict__ probs, float* __restrict__ ctx) {
  __shared__ float att2s[M];            // 8 KB
  __shared__ float masks[M];            // 8 KB
  __shared__ ushort ldsB[2 * 8 * 128 * 8];  // 32 KB (reused for reduction)

  int rt = blockIdx.x & 63;
  int b  = blockIdx.x >> 6;
  int row0 = b * N + rt * 32;
  int t = threadIdx.x;
  int lane = t & 63;
  int w = t >> 6;
  int quad = lane >> 4;
  int l16 = lane & 15;
  int m0w = (w & 1) * 16;  // row slab
  int h   = w >> 1;        // k-chunk half

  // stage batch vectors (conflict-free b128 writes)
#pragma unroll
  for (int i = 0; i < 2; ++i) {
    int idx = (t + i * 256) * 4;
    *(float4*)&att2s[idx] = *(const float4*)(att2 + b * M + idx);
    *(float4*)&masks[idx] = *(const float4*)(mask + b * M + idx);
  }

  int myrow = row0 + m0w + l16;
  float a1v  = att1[myrow];
  float rmxL = rowmax[myrow];
  float rinL = rowinv[myrow];
  float* prow = probs + (size_t)myrow * M;

  f32x4 acc[8] = {};

  for (int k0 = 0; k0 < M; k0 += 128) {
    // stage B: 32 KB contiguous (16 k-groups x 128 e x 8 k bf16)
    {
      const char* g =
          (const char*)(Wb + ((size_t)b * 256 + (k0 >> 3)) * 1024);
      char* l = (char*)ldsB;
      int base = w * 1024 + lane * 16;
#pragma unroll
      for (int i = 0; i < 8; ++i) {
        int off = base + i * 4096;
        __builtin_amdgcn_global_load_lds(
            (const __attribute__((address_space(1))) void*)(g + off),
            (__attribute__((address_space(3))) void*)(l + off), 16, 0, 0);
      }
    }
    __syncthreads();
    int kc = k0 + h * 64;
#pragma unroll
    for (int ks = 0; ks < 64; ks += 32) {
      int kb = kc + ks + quad * 8;
      // vector score reads: quads hit disjoint bank groups, lanes broadcast
      float4 a0 = *(const float4*)&att2s[kb];
      float4 a1q = *(const float4*)&att2s[kb + 4];
      float4 k0v = *(const float4*)&masks[kb];
      float4 k1v = *(const float4*)&masks[kb + 4];
      float p[8];
      p[0] = __expf(leaky_mask(a1v, a0.x, k0v.x) - rmxL) * rinL;
      p[1] = __expf(leaky_mask(a1v, a0.y, k0v.y) - rmxL) * rinL;
      p[2] = __expf(leaky_mask(a1v, a0.z, k0v.z) - rmxL) * rinL;
      p[3] = __expf(leaky_mask(a1v, a0.w, k0v.w) - rmxL) * rinL;
      p[4] = __expf(leaky_mask(a1v, a1q.x, k1v.x) - rmxL) * rinL;
      p[5] = __expf(leaky_mask(a1v, a1q.y, k1v.y) - rmxL) * rinL;
      p[6] = __expf(leaky_mask(a1v, a1q.z, k1v.z) - rmxL) * rinL;
      p[7] = __expf(leaky_mask(a1v, a1q.w, k1v.w) - rmxL) * rinL;
      bf16x8 af;
#pragma unroll
      for (int j = 0; j < 8; ++j) af[j] = (short)f2bf(p[j]);
      *(float4*)(prow + kb)     = make_float4(p[0], p[1], p[2], p[3]);
      *(float4*)(prow + kb + 4) = make_float4(p[4], p[5], p[6], p[7]);
      int gl = h * 8 + (ks >> 3) + quad;
#pragma unroll
      for (int cf = 0; cf < 8; ++cf) {
        int n = cf * 16 + l16;
        bf16x8 bfb = *(const bf16x8*)&ldsB[((size_t)gl * 128 + n) * 8];
        acc[cf] =
            __builtin_amdgcn_mfma_f32_16x16x32_bf16(af, bfb, acc[cf], 0, 0, 0);
      }
    }
    __syncthreads();
  }

  // cross-pair reduction: h==1 waves park accs in LDS (padded stride 36),
  // h==0 waves add and store. Pairs share (w&1) row slab.
  float* red = (float*)ldsB;
  if (h == 1) {
    int base = ((w & 1) * 64 + lane) * 36;
#pragma unroll
    for (int cf = 0; cf < 8; ++cf)
      *(f32x4*)&red[base + cf * 4] = acc[cf];
  }
  __syncthreads();
  if (h == 0) {
    int base = ((w & 1) * 64 + lane) * 36;
#pragma unroll
    for (int cf = 0; cf < 8; ++cf) {
      f32x4 o = *(const f32x4*)&red[base + cf * 4];
      int nn = cf * 16 + l16;
#pragma unroll
      for (int reg = 0; reg < 4; ++reg) {
        int rr = row0 + m0w + quad * 4 + reg;
        ctx[(size_t)rr * E + nn] = acc[cf][reg] + o[reg];
      }
    }
  }
}

extern "C" void kernel_launch(void* const* d_in, const int* in_sizes, int n_in,
                              void* d_out, int out_size, void* d_ws,
                              size_t ws_size, hipStream_t stream) {
  (void)in_sizes; (void)n_in; (void)out_size; (void)ws_size;
  const float* in1  = (const float*)d_in[0];  // (B,N,DIN)
  const float* in2  = (const float*)d_in[1];  // (B,M,DIN)
  const float* mask = (const float*)d_in[2];  // (B,1,M)
  const float* W1   = (const float*)d_in[3];  // (DIN,E)
  const float* a1   = (const float*)d_in[4];  // (2E,1)

  float* ws     = (float*)d_ws;
  float* v1     = ws;                  // 256
  float* v2     = v1 + DIN;            // 256
  float* att1   = v2 + DIN;            // B*N
  float* att2   = att1 + B * N;        // B*M
  float* rowmax = att2 + B * M;        // B*N
  float* rowinv = rowmax + B * N;      // B*N
  ushort* Wb    = (ushort*)(rowinv + B * N);  // B*M*E bf16 packed (8.4 MB)

  float* ctx   = (float*)d_out;                 // B*N*E
  float* probs = ctx + (size_t)B * N * E;       // B*N*M

  hipLaunchKernelGGL(prep_v_kernel, dim3(1), dim3(256), 0, stream, W1, a1, v1, v2);
  hipLaunchKernelGGL(att_kernel, dim3((B * N + B * M) / 4), dim3(256), 0, stream,
                     in1, in2, v1, v2, att1, att2);
  hipLaunchKernelGGL(wh2_kernel, dim3(B * M / 32), dim3(256), 0, stream,
                     in2, W1, Wb);
  hipLaunchKernelGGL(stats_kernel, dim3(B * N / 4), dim3(256), 0, stream,
                     att1, att2, mask, rowmax, rowinv);
  hipLaunchKernelGGL(fused_kernel, dim3(B * N / 32), dim3(256), 0, stream,
                     att1, att2, mask, rowmax, rowinv, Wb, probs, ctx);
}